// Round 6
// baseline (727.132 us; speedup 1.0000x reference)
//
#include <hip/hip_runtime.h>

#define NEGV -10000.0f
constexpr int K  = 128;   // states
constexpr int T  = 512;   // timesteps
constexpr int CH = 8;     // h-prefetch chunk (timesteps)

__device__ __forceinline__ void wait_vm0() {
  asm volatile("s_waitcnt vmcnt(0)" ::: "memory");
}
__device__ __forceinline__ void wait_lgkm0() {
  asm volatile("s_waitcnt lgkmcnt(0)" ::: "memory");
}
// async global -> LDS, 16B/lane; LDS dest = wave-uniform base + lane*16
__device__ __forceinline__ void dma16(const float* g, float* l) {
  __builtin_amdgcn_global_load_lds(
      (const __attribute__((address_space(1))) void*)g,
      (__attribute__((address_space(3))) void*)l, 16, 0, 0);
}
__device__ __forceinline__ float readlane1(float v) {
  return __int_as_float(__builtin_amdgcn_readlane(__float_as_int(v), 1));
}

// One block = one batch row = ONE wave (64 lanes). Lane owns TWO adjacent
// states {2l, 2l+1}; their E-rows (exp(trans)) live in 64 named float4
// registers (256 VGPRs). p is exchanged through 512B of LDS as wave-uniform
// broadcast ds_read_b128 -- and with a SINGLE wave there is NO s_barrier
// anywhere (same-wave DS ops are in-order; compiler inserts the RAW waits).
// This kernel is byte-identical to the R1 variant that PASSED verification
// (absmax 0.0) -- R1 was slow only because the allocator spilled E to
// scratch (172 VGPR). Fix proven in R3: amdgpu_waves_per_eu(1,1) makes the
// allocator honor register demand (52->132 there). Here demand ~300-340 of
// the 512/wave unified file. Eliminates the ~700-900 cyc/step
// write->lgkm->barrier->read turnaround that R0-R4 kept invariant.
__global__ __attribute__((amdgpu_flat_work_group_size(64, 64),
                          amdgpu_waves_per_eu(1, 1)))
void crf_fwd(const float* __restrict__ h, const float* __restrict__ trans,
             const float* __restrict__ mask, float* __restrict__ out) {
  const int lane = threadIdx.x;    // 0..63
  const int b    = blockIdx.x;
  const int j0   = lane << 1;      // states owned: j0, j0+1

  __shared__ __align__(16) float p_lds[K];           // single buffer (1 wave)
  __shared__ __align__(16) float hbuf[2][CH][K];     // double-buffered h chunks

  const float* hb = h + (size_t)b * T * K;

  // ---- async prefetch h chunk 0 (t=0..7): 4 dma16, each covers 2 rows ----
  #pragma unroll
  for (int q = 0; q < 4; ++q)
    dma16(hb + (size_t)(2 * q + (lane >> 5)) * K + 4 * (lane & 31),
          &hbuf[0][2 * q][0]);

  // ---- len = sum(mask[b,:]) (contiguous prefix of 1s); 8 entries/lane ----
  const float4* m4 = reinterpret_cast<const float4*>(mask + (size_t)b * T + 8 * lane);
  const float4 ma = m4[0], mz = m4[1];
  float msum = ((ma.x + ma.y) + (ma.z + ma.w)) + ((mz.x + mz.y) + (mz.z + mz.w));
  #pragma unroll
  for (int off = 32; off > 0; off >>= 1) msum += __shfl_xor(msum, off);
  const int len = (int)(msum + 0.5f);

  // ---- E rows j0, j0+1 in NAMED float4 registers: exp(trans[j,k]) ----
  const float4* ta4 = reinterpret_cast<const float4*>(trans + (size_t)j0 * K);
  const float4* tb4 = reinterpret_cast<const float4*>(trans + (size_t)(j0 + 1) * K);
#define LDE(n) \
  float4 ea##n = ta4[n], eb##n = tb4[n]; \
  ea##n = make_float4(__expf(ea##n.x), __expf(ea##n.y), __expf(ea##n.z), __expf(ea##n.w)); \
  eb##n = make_float4(__expf(eb##n.x), __expf(eb##n.y), __expf(eb##n.z), __expf(eb##n.w));
  LDE(0)  LDE(1)  LDE(2)  LDE(3)  LDE(4)  LDE(5)  LDE(6)  LDE(7)
  LDE(8)  LDE(9)  LDE(10) LDE(11) LDE(12) LDE(13) LDE(14) LDE(15)
  LDE(16) LDE(17) LDE(18) LDE(19) LDE(20) LDE(21) LDE(22) LDE(23)
  LDE(24) LDE(25) LDE(26) LDE(27) LDE(28) LDE(29) LDE(30) LDE(31)
#undef LDE
  const float2 trE = *reinterpret_cast<const float2*>(trans + K + j0); // trans[EOS=1, j0..j0+1]

  // ---- init: p(0) one-hot at SOS ----
  *reinterpret_cast<float2*>(&p_lds[j0]) = make_float2(j0 == 0 ? 1.0f : 0.0f, 0.0f);
  wait_lgkm0();

  float Scur = 0.0f;   // shift baked into the p we are about to read
  float Strk = 0.0f;   // tracker: fs(state 2) of previous step (1-step stale)
  float fs0 = NEGV, fs1 = NEGV;
  int cur = 0;

  for (int t = 0; t < len; ++t) {
    const int cpos = t & (CH - 1);
    if (cpos == 0) {                 // chunk boundary
      wait_vm0();
      cur = (t >> 3) & 1;
      const int tn = t + CH;
      if (tn < len) {
        #pragma unroll
        for (int q = 0; q < 4; ++q)
          dma16(hb + (size_t)(tn + 2 * q + (lane >> 5)) * K + 4 * (lane & 31),
                &hbuf[cur ^ 1][2 * q][0]);
      }
    }

    const float Snext = Strk;                               // S_{t+1} (stale)
    const float2 hv = *reinterpret_cast<const float2*>(&hbuf[cur][cpos][j0]);

    // full 128-wide dot for BOTH owned states; p reads are broadcast b128
    const float4* p4 = reinterpret_cast<const float4*>(p_lds);
    float a0 = 0.f, a1 = 0.f, a2 = 0.f, a3 = 0.f;
    float c0 = 0.f, c1 = 0.f, c2 = 0.f, c3 = 0.f;
#define DOT(n) { const float4 pv = p4[n]; \
    a0 += ea##n.x * pv.x; a1 += ea##n.y * pv.y; a2 += ea##n.z * pv.z; a3 += ea##n.w * pv.w; \
    c0 += eb##n.x * pv.x; c1 += eb##n.y * pv.y; c2 += eb##n.z * pv.z; c3 += eb##n.w * pv.w; }
    DOT(0)  DOT(1)  DOT(2)  DOT(3)  DOT(4)  DOT(5)  DOT(6)  DOT(7)
    DOT(8)  DOT(9)  DOT(10) DOT(11) DOT(12) DOT(13) DOT(14) DOT(15)
    DOT(16) DOT(17) DOT(18) DOT(19) DOT(20) DOT(21) DOT(22) DOT(23)
    DOT(24) DOT(25) DOT(26) DOT(27) DOT(28) DOT(29) DOT(30) DOT(31)
#undef DOT
    const float tot0 = (a0 + a1) + (a2 + a3);
    const float tot1 = (c0 + c1) + (c2 + c3);

    // off-critical-path factor: g = exp(h + S_t - S_{t+1})
    const float g0 = __expf(hv.x + Scur - Snext);
    const float g1 = __expf(hv.y + Scur - Snext);
    *reinterpret_cast<float2*>(&p_lds[j0]) = make_float2(tot0 * g0, tot1 * g1);

    fs0 = hv.x + Scur + __logf(tot0);                       // true score_{j0}(t)
    fs1 = hv.y + Scur + __logf(tot1);                       // true score_{j0+1}(t)
    Strk = readlane1(fs0);                                  // state j=2 lives in lane 1
    Scur = Snext;
  }

  // ---- epilogue: out[b] = logsumexp_j(fs_j + trans[EOS, j]) ----
  const float f0 = fs0 + trE.x;
  const float f1 = fs1 + trE.y;
  float m = fmaxf(f0, f1);
  #pragma unroll
  for (int off = 32; off > 0; off >>= 1) m = fmaxf(m, __shfl_xor(m, off));
  float e = __expf(f0 - m) + __expf(f1 - m);
  #pragma unroll
  for (int off = 32; off > 0; off >>= 1) e += __shfl_xor(e, off);
  if (lane == 0) out[b] = m + __logf(e);
}

extern "C" void kernel_launch(void* const* d_in, const int* in_sizes, int n_in,
                              void* d_out, int out_size, void* d_ws, size_t ws_size,
                              hipStream_t stream) {
  const float* h     = (const float*)d_in[0];  // (B,T,K) fp32
  const float* trans = (const float*)d_in[1];  // (K,K)   fp32
  const float* mask  = (const float*)d_in[2];  // (B,T)   fp32
  float* out = (float*)d_out;                  // (B,)    fp32
  const int B = in_sizes[0] / (T * K);         // 256
  crf_fwd<<<B, 64, 0, stream>>>(h, trans, mask, out);
}

// Round 8
// 319.607 us; speedup vs baseline: 2.2751x; 2.2751x over previous
//
#include <hip/hip_runtime.h>

#define NEGV -10000.0f
constexpr int K  = 128;   // states
constexpr int T  = 512;   // timesteps
constexpr int CH = 8;     // h-prefetch chunk (timesteps)

typedef float f32x2 __attribute__((ext_vector_type(2)));
typedef float f32x4 __attribute__((ext_vector_type(4)));

// s_barrier WITHOUT the compiler's vmcnt(0) drain.
__device__ __forceinline__ void bar_lgkm() {
  asm volatile("s_waitcnt lgkmcnt(0)\n\ts_barrier" ::: "memory");
}
__device__ __forceinline__ void wait_vm0() {
  asm volatile("s_waitcnt vmcnt(0)" ::: "memory");
}
// async global -> LDS, 16B/lane; LDS dest = wave-uniform base + lane*16
__device__ __forceinline__ void dma16(const float* g, float* l) {
  __builtin_amdgcn_global_load_lds(
      (const __attribute__((address_space(1))) void*)g,
      (__attribute__((address_space(3))) void*)l, 16, 0, 0);
}
// add the quad-mate's value (lanes 2m <-> 2m+1): VALU DPP, no LDS pipe
__device__ __forceinline__ float pair_sum(float x) {
  int o = __builtin_amdgcn_update_dpp(0, __float_as_int(x), 0xB1, 0xF, 0xF, true);
  return x + __int_as_float(o);
}

#if __has_builtin(__builtin_elementwise_fma)
#define VFMA(a, b, c) __builtin_elementwise_fma((a), (b), (c))
#else
__device__ __forceinline__ f32x2 VFMA(f32x2 a, f32x2 b, f32x2 c) {
  f32x2 r; r.x = fmaf(a.x, b.x, c.x); r.y = fmaf(a.y, b.y, c.y); return r;
}
#endif

// R4 structure (2 waves, 128 threads, thread = (state-pair, k-half)) with
// three surgical changes, motivated by R6's finding that v0-v255 is the
// addressable-VGPR wall (single-wave 256-E design impossible) and that
// R4's VGPR=132 means E was re-loaded from L2 every step (~64 VMEM/CU/step
// + ~200cyc tail inside the 1261-cyc chain):
//  1. E pinned in registers via empty asm "+v" on the split f32x2 values
//     (loop consumes asm OUTPUTS -> cannot be re-sunk; ~180 regs < 256).
//  2. 8-step unrolled chunks: rescale shift S updated only at chunk
//     boundaries (p bounded by ~e^65 worst case, fp32-safe; exact math
//     identical), logs only at cpos==7 / t==len-1, static LDS indices.
//  3. f32x2 packed dot (v_pk_fma_f32), halving dot issue; association
//     order (a0+a1)+(a2+a3) preserved bit-exactly.
// (R7 was a compile fix only: macro temp names ta4/tb4 collided with the
// pointer variables; pointers renamed pEa/pEb, temps va##n/vb##n.)
__global__ __attribute__((amdgpu_flat_work_group_size(128, 128),
                          amdgpu_waves_per_eu(1, 1)))
void crf_fwd(const float* __restrict__ h, const float* __restrict__ trans,
             const float* __restrict__ mask, float* __restrict__ out) {
  const int tid  = threadIdx.x;    // 0..127
  const int b    = blockIdx.x;
  const int wid  = tid >> 6;       // wave id 0..1
  const int lane = tid & 63;
  const int mi   = lane >> 1;      // state-pair index within wave, 0..31
  const int half = tid & 1;        // which 64-wide k-slice
  const int s0   = 64 * wid + 2 * mi;  // states owned: s0, s0+1

  __shared__ __align__(16) float p_lds[2][K];          // double-buffered p
  __shared__ __align__(16) float hb3[2][2][CH][64];    // [buf][wave][row][col64]
  __shared__ float Mslot[2];                           // tracker, per-chunk parity
  __shared__ float red[4];

  // ---- len = sum(mask[b,:]) (contiguous prefix of 1s); 4 floats/thread ----
  const f32x4 mv = reinterpret_cast<const f32x4*>(mask + (size_t)b * T)[tid];
  float msum = (mv.x + mv.y) + (mv.z + mv.w);
  #pragma unroll
  for (int off = 32; off > 0; off >>= 1) msum += __shfl_xor(msum, off);
  if (lane == 0) red[wid] = msum;

  // ---- E rows s0, s0+1 over k-half: exp(trans), split into f32x2 pairs ----
  const f32x4* pEa = reinterpret_cast<const f32x4*>(trans + (size_t)s0 * K + 64 * half);
  const f32x4* pEb = reinterpret_cast<const f32x4*>(trans + (size_t)(s0 + 1) * K + 64 * half);
#define LDE(n) \
  f32x4 va##n = pEa[n], vb##n = pEb[n]; \
  va##n.x = __expf(va##n.x); va##n.y = __expf(va##n.y); \
  va##n.z = __expf(va##n.z); va##n.w = __expf(va##n.w); \
  vb##n.x = __expf(vb##n.x); vb##n.y = __expf(vb##n.y); \
  vb##n.z = __expf(vb##n.z); vb##n.w = __expf(vb##n.w); \
  f32x2 eal##n = __builtin_shufflevector(va##n, va##n, 0, 1); \
  f32x2 eah##n = __builtin_shufflevector(va##n, va##n, 2, 3); \
  f32x2 ebl##n = __builtin_shufflevector(vb##n, vb##n, 0, 1); \
  f32x2 ebh##n = __builtin_shufflevector(vb##n, vb##n, 2, 3);
  LDE(0)  LDE(1)  LDE(2)  LDE(3)  LDE(4)  LDE(5)  LDE(6)  LDE(7)
  LDE(8)  LDE(9)  LDE(10) LDE(11) LDE(12) LDE(13) LDE(14) LDE(15)
#undef LDE
  // Pin the 64 f32x2 E values: loop uses the asm OUTPUTS -> loads cannot be
  // sunk into the loop, values cannot be rematerialized; RA keeps them live.
#define PIN(n) asm volatile("" : "+v"(eal##n), "+v"(eah##n), "+v"(ebl##n), "+v"(ebh##n));
  PIN(0)  PIN(1)  PIN(2)  PIN(3)  PIN(4)  PIN(5)  PIN(6)  PIN(7)
  PIN(8)  PIN(9)  PIN(10) PIN(11) PIN(12) PIN(13) PIN(14) PIN(15)
#undef PIN
  const f32x2 trE = *reinterpret_cast<const f32x2*>(trans + K + s0); // trans[EOS=1, s0..s0+1]

  // ---- async prefetch of h chunk 0; wave-private 64-col slices ----
  const float* hb = h + (size_t)b * T * K;
  #pragma unroll
  for (int r = 0; r < 2; ++r)
    dma16(hb + (size_t)(4 * r + (lane >> 4)) * K + 64 * wid + 4 * (lane & 15),
          &hb3[0][wid][4 * r][0]);

  // ---- init: p(0) one-hot at SOS; tracker = 0 ----
  p_lds[0][tid] = (tid == 0) ? 1.0f : 0.0f;
  if (tid < 2) Mslot[tid] = 0.0f;
  bar_lgkm();

  const int len = (int)(red[0] + red[1] + 0.5f);
  const int nch = (len + CH - 1) >> 3;   // number of 8-step chunks

  float Scur = 0.0f;            // shift of the p about to be read
  float fs0 = NEGV, fs1 = NEGV; // true scores of owned states at last step

  for (int mc = 0; mc < nch; ++mc) {
    const int base = mc << 3;
    const int cur  = mc & 1;
    #pragma unroll
    for (int c = 0; c < CH; ++c) {
      const int t = base + c;
      if (t >= len) break;               // uniform per block
      bar_lgkm();                        // p(t), Mslot writes now visible

      float Snext = Scur;
      if (c == 0) {                      // chunk boundary
        wait_vm0();
        const int tn = t + CH;
        if (tn < len) {
          #pragma unroll
          for (int r = 0; r < 2; ++r)
            dma16(hb + (size_t)(tn + 4 * r + (lane >> 4)) * K + 64 * wid + 4 * (lane & 15),
                  &hb3[cur ^ 1][wid][4 * r][0]);
        }
        if (mc) Snext = Mslot[mc & 1];   // fresh tracker (written at cpos 7)
      }

      const f32x2 hv = *reinterpret_cast<const f32x2*>(&hb3[cur][wid][c][2 * mi]);

      // 64-wide half-dots for BOTH owned states, packed f32x2 FMAs
      const f32x4* p4 = reinterpret_cast<const f32x4*>(&p_lds[c & 1][64 * half]);
      f32x2 a01 = {0.f, 0.f}, a23 = {0.f, 0.f};
      f32x2 c01 = {0.f, 0.f}, c23 = {0.f, 0.f};
#define DOT(n) { const f32x4 pv = p4[n]; \
      const f32x2 pl = __builtin_shufflevector(pv, pv, 0, 1); \
      const f32x2 ph = __builtin_shufflevector(pv, pv, 2, 3); \
      a01 = VFMA(eal##n, pl, a01); a23 = VFMA(eah##n, ph, a23); \
      c01 = VFMA(ebl##n, pl, c01); c23 = VFMA(ebh##n, ph, c23); }
      DOT(0)  DOT(1)  DOT(2)  DOT(3)  DOT(4)  DOT(5)  DOT(6)  DOT(7)
      DOT(8)  DOT(9)  DOT(10) DOT(11) DOT(12) DOT(13) DOT(14) DOT(15)
#undef DOT
      const float tot0 = pair_sum((a01.x + a01.y) + (a23.x + a23.y));
      const float tot1 = pair_sum((c01.x + c01.y) + (c23.x + c23.y));

      // g = exp(h + S_read - S_next); within chunk S_next == S_read -> exp(h)
      const float d  = Scur - Snext;
      const float g0 = __expf(hv.x + d);
      const float g1 = __expf(hv.y + d);
      f32x2 pw; pw.x = tot0 * g0; pw.y = tot1 * g1;
      *reinterpret_cast<f32x2*>(&p_lds[(c & 1) ^ 1][s0]) = pw;

      if (c == CH - 1 || t == len - 1) { // logs off the per-step path
        fs0 = hv.x + Scur + __logf(tot0);
        fs1 = hv.y + Scur + __logf(tot1);
        if (tid == 2) Mslot[(mc + 1) & 1] = fs0;  // tracker = state j=2
      }
      Scur = Snext;
    }
  }

  // ---- epilogue: out[b] = logsumexp_j(fs_j + trans[EOS, j]) ----
  const float f0 = fs0 + trE.x;
  const float f1 = fs1 + trE.y;
  float mx = fmaxf(f0, f1);
  #pragma unroll
  for (int off = 32; off > 0; off >>= 1) mx = fmaxf(mx, __shfl_xor(mx, off));
  if (lane == 0) red[wid] = mx;
  bar_lgkm();
  const float fm = fmaxf(red[0], red[1]);
  float e = (half == 0) ? (__expf(f0 - fm) + __expf(f1 - fm)) : 0.0f; // de-dup pair
  #pragma unroll
  for (int off = 32; off > 0; off >>= 1) e += __shfl_xor(e, off);
  if (lane == 0) red[2 + wid] = e;
  bar_lgkm();
  if (tid == 0) out[b] = fm + __logf(red[2] + red[3]);
}

extern "C" void kernel_launch(void* const* d_in, const int* in_sizes, int n_in,
                              void* d_out, int out_size, void* d_ws, size_t ws_size,
                              hipStream_t stream) {
  const float* h     = (const float*)d_in[0];  // (B,T,K) fp32
  const float* trans = (const float*)d_in[1];  // (K,K)   fp32
  const float* mask  = (const float*)d_in[2];  // (B,T)   fp32
  float* out = (float*)d_out;                  // (B,)    fp32
  const int B = in_sizes[0] / (T * K);         // 256
  crf_fwd<<<B, 128, 0, stream>>>(h, trans, mask, out);
}

// Round 9
// 267.157 us; speedup vs baseline: 2.7217x; 1.1963x over previous
//
#include <hip/hip_runtime.h>

#define NEGV -10000.0f
constexpr int K  = 128;   // states
constexpr int T  = 512;   // timesteps
constexpr int CH = 8;     // h-prefetch chunk (timesteps)

typedef float f32x2 __attribute__((ext_vector_type(2)));
typedef float f32x4 __attribute__((ext_vector_type(4)));

// s_barrier WITHOUT the compiler's vmcnt(0) drain.
__device__ __forceinline__ void bar_lgkm() {
  asm volatile("s_waitcnt lgkmcnt(0)\n\ts_barrier" ::: "memory");
}
__device__ __forceinline__ void wait_vm0() {
  asm volatile("s_waitcnt vmcnt(0)" ::: "memory");
}
// async global -> LDS, 16B/lane; LDS dest = wave-uniform base + lane*16
__device__ __forceinline__ void dma16(const float* g, float* l) {
  __builtin_amdgcn_global_load_lds(
      (const __attribute__((address_space(1))) void*)g,
      (__attribute__((address_space(3))) void*)l, 16, 0, 0);
}
template <int CTRL>
__device__ __forceinline__ float dpp_add(float x) {
  int o = __builtin_amdgcn_update_dpp(0, __float_as_int(x), CTRL, 0xF, 0xF, true);
  return x + __int_as_float(o);
}
// sum across the 8 lanes of an oct-group (lanes 8m..8m+7): 3 DPP steps
__device__ __forceinline__ float sum8(float x) {
  x = dpp_add<0xB1>(x);    // + lane^1 (quad_perm [1,0,3,2])
  x = dpp_add<0x4E>(x);    // + lane^2 (quad_perm [2,3,0,1])
  x = dpp_add<0x141>(x);   // + other quad (row_half_mirror)
  return x;
}

#if __has_builtin(__builtin_elementwise_fma)
#define VFMA(a, b, c) __builtin_elementwise_fma((a), (b), (c))
#else
__device__ __forceinline__ f32x2 VFMA(f32x2 a, f32x2 b, f32x2 c) {
  f32x2 r; r.x = fmaf(a.x, b.x, c.x); r.y = fmaf(a.y, b.y, c.y); return r;
}
#endif

// S=4 structure. R8 post-mortem: every non-E-resident variant is L2-BW
// bound on E refetch (8.6GB / 250us = 34.4 TB/s = the L2 ceiling; per-CU
// 64KB/step / 56B/cyc = 1170 cyc = R8's measured 1172). RA grants ~132
// regs (64 E floats/thread, R3) but refuses 128/thread (R4/R8). So:
// 4 waves, thread = (group of 4 states, 16-wide k-slice oct): E = 64
// floats/thread (RA-proven resident) AND p-read LDS instrs drop to
// 4/thread (per-CU 16 vs R8's 32). Combine over 8 lanes = 3 DPP steps.
// Per-oct k-chunk rotation k_j = 16*oct + 4*((j+(oct>>1))&3), applied to
// BOTH the E-register load and the p-read, makes the 8 lines per read
// instruction distinct mod 8 -> conflict-free broadcast. Carries R8's
// chunk-stale rescale, packed v_pk_fma_f32, and the E-pin asm.
__global__ __attribute__((amdgpu_flat_work_group_size(256, 256),
                          amdgpu_waves_per_eu(1, 1)))
void crf_fwd(const float* __restrict__ h, const float* __restrict__ trans,
             const float* __restrict__ mask, float* __restrict__ out) {
  const int tid  = threadIdx.x;     // 0..255
  const int b    = blockIdx.x;
  const int wid  = tid >> 6;        // wave 0..3
  const int lane = tid & 63;
  const int gl   = lane >> 3;       // group-in-wave 0..7
  const int oct  = lane & 7;        // k-slice 0..7
  const int sb   = 4 * (8 * wid + gl);  // states sb..sb+3
  const int rot  = oct >> 1;
  const int k0   = 16 * oct + 4 * ((0 + rot) & 3);
  const int k1   = 16 * oct + 4 * ((1 + rot) & 3);
  const int k2   = 16 * oct + 4 * ((2 + rot) & 3);
  const int k3   = 16 * oct + 4 * ((3 + rot) & 3);

  __shared__ __align__(16) float p_lds[2][K];          // double-buffered p
  __shared__ __align__(16) float hbuf[2][4][CH][32];   // [buf][wave][row][col]
  __shared__ float Mslot[2];                           // tracker, per-chunk parity
  __shared__ float red[8];

  // ---- len = sum(mask[b,:]) (contiguous prefix of 1s) ----
  float msum = mask[b * T + tid] + mask[b * T + 256 + tid];
  #pragma unroll
  for (int off = 32; off > 0; off >>= 1) msum += __shfl_xor(msum, off);
  if (lane == 0) red[wid] = msum;

  // ---- async prefetch of h chunk 0; wave w loads its own 32-col slice ----
  const float* hb = h + (size_t)b * T * K;
  dma16(hb + (size_t)(lane >> 3) * K + 32 * wid + 4 * (lane & 7),
        &hbuf[0][wid][0][0]);

  // ---- E: 4 states x 16 k-floats in NAMED registers, exp'd, f32x2-split ----
#define EXP4(v) v.x = __expf(v.x); v.y = __expf(v.y); \
                v.z = __expf(v.z); v.w = __expf(v.w);
#define LDE(si) \
  const float* rp##si = trans + (size_t)(sb + si) * K; \
  f32x4 w##si##0 = *reinterpret_cast<const f32x4*>(rp##si + k0); \
  f32x4 w##si##1 = *reinterpret_cast<const f32x4*>(rp##si + k1); \
  f32x4 w##si##2 = *reinterpret_cast<const f32x4*>(rp##si + k2); \
  f32x4 w##si##3 = *reinterpret_cast<const f32x4*>(rp##si + k3); \
  EXP4(w##si##0) EXP4(w##si##1) EXP4(w##si##2) EXP4(w##si##3) \
  f32x2 E##si##0l = __builtin_shufflevector(w##si##0, w##si##0, 0, 1); \
  f32x2 E##si##0h = __builtin_shufflevector(w##si##0, w##si##0, 2, 3); \
  f32x2 E##si##1l = __builtin_shufflevector(w##si##1, w##si##1, 0, 1); \
  f32x2 E##si##1h = __builtin_shufflevector(w##si##1, w##si##1, 2, 3); \
  f32x2 E##si##2l = __builtin_shufflevector(w##si##2, w##si##2, 0, 1); \
  f32x2 E##si##2h = __builtin_shufflevector(w##si##2, w##si##2, 2, 3); \
  f32x2 E##si##3l = __builtin_shufflevector(w##si##3, w##si##3, 0, 1); \
  f32x2 E##si##3h = __builtin_shufflevector(w##si##3, w##si##3, 2, 3);
  LDE(0) LDE(1) LDE(2) LDE(3)
#undef LDE
#undef EXP4
#define PIN(si) asm volatile("" : "+v"(E##si##0l), "+v"(E##si##0h), \
    "+v"(E##si##1l), "+v"(E##si##1h), "+v"(E##si##2l), "+v"(E##si##2h), \
    "+v"(E##si##3l), "+v"(E##si##3h));
  PIN(0) PIN(1) PIN(2) PIN(3)
#undef PIN
  const f32x4 trE = *reinterpret_cast<const f32x4*>(trans + K + sb); // trans[EOS=1, sb..sb+3]

  // ---- init: p(0) one-hot at SOS; tracker = 0 ----
  if (tid < K) p_lds[0][tid] = (tid == 0) ? 1.0f : 0.0f;
  if (tid < 2) Mslot[tid] = 0.0f;
  bar_lgkm();

  const int len = (int)(red[0] + red[1] + red[2] + red[3] + 0.5f);
  const int nch = (len + CH - 1) >> 3;

  float Scur = 0.0f;            // shift of the p about to be read
  float fsA = NEGV, fsB = NEGV, fsC = NEGV, fsD = NEGV;

  for (int mc = 0; mc < nch; ++mc) {
    const int base = mc << 3;
    const int cur  = mc & 1;
    #pragma unroll
    for (int c = 0; c < CH; ++c) {
      const int t = base + c;
      if (t >= len) break;               // uniform per block
      bar_lgkm();                        // p(t), Mslot writes now visible

      float Snext = Scur;
      if (c == 0) {                      // chunk boundary
        wait_vm0();
        const int tn = t + CH;
        if (tn < len) {
          dma16(hb + (size_t)(tn + (lane >> 3)) * K + 32 * wid + 4 * (lane & 7),
                &hbuf[cur ^ 1][wid][0][0]);
        }
        if (mc) Snext = Mslot[mc & 1];   // fresh tracker (written at cpos 7)
      }

      const f32x4 hv4 = *reinterpret_cast<const f32x4*>(&hbuf[cur][wid][c][4 * gl]);

      // 16-wide slice dots for 4 states; rotated conflict-free b128 reads
      const float* pb = p_lds[c & 1];
      f32x4 q0 = *reinterpret_cast<const f32x4*>(pb + k0);
      f32x4 q1 = *reinterpret_cast<const f32x4*>(pb + k1);
      f32x4 q2 = *reinterpret_cast<const f32x4*>(pb + k2);
      f32x4 q3 = *reinterpret_cast<const f32x4*>(pb + k3);
      f32x2 q0l = __builtin_shufflevector(q0, q0, 0, 1);
      f32x2 q0h = __builtin_shufflevector(q0, q0, 2, 3);
      f32x2 q1l = __builtin_shufflevector(q1, q1, 0, 1);
      f32x2 q1h = __builtin_shufflevector(q1, q1, 2, 3);
      f32x2 q2l = __builtin_shufflevector(q2, q2, 0, 1);
      f32x2 q2h = __builtin_shufflevector(q2, q2, 2, 3);
      f32x2 q3l = __builtin_shufflevector(q3, q3, 0, 1);
      f32x2 q3h = __builtin_shufflevector(q3, q3, 2, 3);
#define DOTSI(si) \
      f32x2 aa##si = {0.f, 0.f}, ab##si = {0.f, 0.f}; \
      aa##si = VFMA(E##si##0l, q0l, aa##si); ab##si = VFMA(E##si##0h, q0h, ab##si); \
      aa##si = VFMA(E##si##1l, q1l, aa##si); ab##si = VFMA(E##si##1h, q1h, ab##si); \
      aa##si = VFMA(E##si##2l, q2l, aa##si); ab##si = VFMA(E##si##2h, q2h, ab##si); \
      aa##si = VFMA(E##si##3l, q3l, aa##si); ab##si = VFMA(E##si##3h, q3h, ab##si); \
      const float tot##si = sum8((aa##si.x + aa##si.y) + (ab##si.x + ab##si.y));
      DOTSI(0) DOTSI(1) DOTSI(2) DOTSI(3)
#undef DOTSI

      // g = exp(h + S_read - S_next); within chunk S_next == S_read
      const float d = Scur - Snext;
      f32x4 pw;
      pw.x = tot0 * __expf(hv4.x + d);
      pw.y = tot1 * __expf(hv4.y + d);
      pw.z = tot2 * __expf(hv4.z + d);
      pw.w = tot3 * __expf(hv4.w + d);
      if (oct == 0)
        *reinterpret_cast<f32x4*>(&p_lds[(c & 1) ^ 1][sb]) = pw;

      if (c == CH - 1 || t == len - 1) { // logs off the per-step path
        fsA = hv4.x + Scur + __logf(tot0);
        fsB = hv4.y + Scur + __logf(tot1);
        fsC = hv4.z + Scur + __logf(tot2);
        fsD = hv4.w + Scur + __logf(tot3);
        if (tid == 0) Mslot[(mc + 1) & 1] = fsC;   // tracker = state j=2
      }
      Scur = Snext;
    }
  }

  // ---- epilogue: out[b] = logsumexp_j(fs_j + trans[EOS, j]) ----
  f32x4 ff;
  ff.x = fsA + trE.x; ff.y = fsB + trE.y;
  ff.z = fsC + trE.z; ff.w = fsD + trE.w;
  float mx = fmaxf(fmaxf(ff.x, ff.y), fmaxf(ff.z, ff.w));
  #pragma unroll
  for (int off = 32; off > 0; off >>= 1) mx = fmaxf(mx, __shfl_xor(mx, off));
  if (lane == 0) red[wid] = mx;
  bar_lgkm();
  const float fm = fmaxf(fmaxf(red[0], red[1]), fmaxf(red[2], red[3]));
  float e = 0.0f;
  if (oct == 0)                         // de-dup the 8 slice copies
    e = (__expf(ff.x - fm) + __expf(ff.y - fm)) +
        (__expf(ff.z - fm) + __expf(ff.w - fm));
  #pragma unroll
  for (int off = 32; off > 0; off >>= 1) e += __shfl_xor(e, off);
  if (lane == 0) red[4 + wid] = e;
  bar_lgkm();
  if (tid == 0) out[b] = fm + __logf((red[4] + red[5]) + (red[6] + red[7]));
}

extern "C" void kernel_launch(void* const* d_in, const int* in_sizes, int n_in,
                              void* d_out, int out_size, void* d_ws, size_t ws_size,
                              hipStream_t stream) {
  const float* h     = (const float*)d_in[0];  // (B,T,K) fp32
  const float* trans = (const float*)d_in[1];  // (K,K)   fp32
  const float* mask  = (const float*)d_in[2];  // (B,T)   fp32
  float* out = (float*)d_out;                  // (B,)    fp32
  const int B = in_sizes[0] / (T * K);         // 256
  crf_fwd<<<B, 256, 0, stream>>>(h, trans, mask, out);
}